// Round 8
// baseline (7271.692 us; speedup 1.0000x reference)
//
#include <hip/hip_runtime.h>
#include <hip/hip_bf16.h>
#include <math.h>

#define B_ 32
#define T_ 512
#define D_ 1024
#define H_ 1024
#define G4 4096
#define BT 16384
#define NWG 64

using bf16x8 = __attribute__((ext_vector_type(8))) short;
using f32x4  = __attribute__((ext_vector_type(4))) float;
typedef unsigned long long u64;
typedef unsigned int u32;

__device__ __forceinline__ float sigm(float x) { return 1.0f / (1.0f + __expf(-x)); }

// ---- workspace layout (bytes) ----
#define OFF_TB    0ull                          // tagged h dbuf [2][32][512] u64 = 262144
#define OFF_WHB   262144ull                     // Wh bf16 [4096][1024] = 8388608
#define OFF_WXB   (OFF_WHB + 8388608ull)        // Wx bf16 = 8388608
#define OFF_INPB  (OFF_WXB + 8388608ull)        // inp bf16 [BT][D] = 33554432
#define OFF_BXH   (OFF_INPB + 33554432ull)      // bx+bh f32 [4096] = 16384
#define OFF_XG    (OFF_BXH + 16384ull)          // xg bf16 [T][NWG][4][32][16] = 134217728
#define WS_NEEDED (OFF_XG + 134217728ull)       // = 184827904

// scan LDS: [0,65536) h-stage 32x2048B swizzled; [65536,74240) gbuf [32][4][17] f32
#define SMEM_GBUF   65536
#define SMEM_TOTAL  74240

// ============ phase 1: convert inputs to bf16, fold biases ============
__global__ __launch_bounds__(256) void convert_all(
    const float* __restrict__ inp, const float* __restrict__ Wx,
    const float* __restrict__ bx, const float* __restrict__ Wh,
    const float* __restrict__ bh,
    __hip_bfloat16* __restrict__ inp_b, __hip_bfloat16* __restrict__ Wx_b,
    __hip_bfloat16* __restrict__ Wh_b, float* __restrict__ bxh)
{
    const int gid = blockIdx.x * 256 + threadIdx.x;   // 0 .. 1048575
    {
        const float4* s = (const float4*)inp + (size_t)gid * 4;
        #pragma unroll
        for (int v = 0; v < 4; ++v) {
            float4 f = s[v];
            size_t base = (size_t)gid * 16 + v * 4;
            inp_b[base + 0] = __float2bfloat16(f.x);
            inp_b[base + 1] = __float2bfloat16(f.y);
            inp_b[base + 2] = __float2bfloat16(f.z);
            inp_b[base + 3] = __float2bfloat16(f.w);
        }
    }
    {
        float4 fx = ((const float4*)Wx)[gid];
        float4 fh = ((const float4*)Wh)[gid];
        size_t base = (size_t)gid * 4;
        Wx_b[base + 0] = __float2bfloat16(fx.x);
        Wx_b[base + 1] = __float2bfloat16(fx.y);
        Wx_b[base + 2] = __float2bfloat16(fx.z);
        Wx_b[base + 3] = __float2bfloat16(fx.w);
        Wh_b[base + 0] = __float2bfloat16(fh.x);
        Wh_b[base + 1] = __float2bfloat16(fh.y);
        Wh_b[base + 2] = __float2bfloat16(fh.z);
        Wh_b[base + 3] = __float2bfloat16(fh.w);
    }
    if (gid < G4) bxh[gid] = bx[gid] + bh[gid];
}

// ============ phase 2: xg = X @ Wx^T + (bx+bh)  (128x128 LDS-staged, T2 swizzle) ============
__global__ __launch_bounds__(256) void xg_gemm(
    const __hip_bfloat16* __restrict__ X,    // [BT][D], row = b*T + t
    const __hip_bfloat16* __restrict__ Wxb,  // [G4][D]
    const float* __restrict__ bxh,           // [G4]
    __hip_bfloat16* __restrict__ xg)         // [T][NWG][4][32][16]
{
    __shared__ __align__(16) char As[16384];
    __shared__ __align__(16) char Bs[16384];

    const int m0 = blockIdx.x * 128;
    const int n0 = blockIdx.y * 128;
    const int tid = threadIdx.x;
    const int lane = tid & 63;
    const int wv = tid >> 6;              // 0..3
    const int vr = wv >> 1, vc = wv & 1;  // 64x64 quadrant
    const int l15 = lane & 15;
    const int kg = (lane >> 4) * 8;

    const int srow_ = wv * 32 + (lane >> 3);
    const int scolb = (lane & 7) * 16;

    f32x4 acc[4][4] = {};

    for (int k0 = 0; k0 < D_; k0 += 64) {
        #pragma unroll
        for (int c = 0; c < 4; ++c) {
            const int row = srow_ + c * 8;
            const int cb  = scolb ^ ((row & 7) << 4);
            const char* ga = (const char*)X   + (size_t)(m0 + row) * 2048 + k0 * 2 + cb;
            const char* gb = (const char*)Wxb + (size_t)(n0 + row) * 2048 + k0 * 2 + cb;
            __builtin_amdgcn_global_load_lds(
                (const __attribute__((address_space(1))) void*)ga,
                (__attribute__((address_space(3))) void*)(As + wv * 4096 + c * 1024),
                16, 0, 0);
            __builtin_amdgcn_global_load_lds(
                (const __attribute__((address_space(1))) void*)gb,
                (__attribute__((address_space(3))) void*)(Bs + wv * 4096 + c * 1024),
                16, 0, 0);
        }
        __syncthreads();

        #pragma unroll
        for (int kk = 0; kk < 64; kk += 32) {
            bf16x8 af[4], bf[4];
            #pragma unroll
            for (int mi = 0; mi < 4; ++mi) {
                const int row = vr * 64 + mi * 16 + l15;
                af[mi] = *(const bf16x8*)(As + row * 128 + (((kk + kg) * 2) ^ ((row & 7) << 4)));
            }
            #pragma unroll
            for (int ni = 0; ni < 4; ++ni) {
                const int col = vc * 64 + ni * 16 + l15;
                bf[ni] = *(const bf16x8*)(Bs + col * 128 + (((kk + kg) * 2) ^ ((col & 7) << 4)));
            }
            #pragma unroll
            for (int mi = 0; mi < 4; ++mi)
                #pragma unroll
                for (int ni = 0; ni < 4; ++ni)
                    acc[mi][ni] = __builtin_amdgcn_mfma_f32_16x16x32_bf16(
                        af[mi], bf[ni], acc[mi][ni], 0, 0, 0);
        }
        __syncthreads();
    }

    #pragma unroll
    for (int ni = 0; ni < 4; ++ni) {
        const int col = n0 + vc * 64 + ni * 16 + l15;
        const int qq = col >> 10, ww = (col >> 4) & 63, jj = col & 15;
        const float bias = bxh[col];
        #pragma unroll
        for (int mi = 0; mi < 4; ++mi) {
            const int r0 = m0 + vr * 64 + mi * 16 + ((lane >> 4) << 2);
            #pragma unroll
            for (int r = 0; r < 4; ++r) {
                const int row = r0 + r;                 // = b*T + t
                const int bb = row >> 9, tt = row & 511;
                xg[(((size_t)tt * NWG + ww) * 4 + qq) * 512 + bb * 16 + jj] =
                    __float2bfloat16(acc[mi][ni][r] + bias);
            }
        }
    }
}

// ============ phase 3: persistent recurrent scan — tag-in-data sync ============
// 64 WGs x 512 threads. h exchanged as tagged u64 granules in tb[2][B][H/2]:
//   granule = (bf16 h[2j+1] | h[2j] << ...) in high u32, step tag in low u32.
// Consumers retry UC loads until tag matches -> single fabric RT for sync+data.
// 2 barriers/step. f32 out written directly (off critical path). No flags, no fences.
__global__ __launch_bounds__(512) void lstm_scan(
    const __hip_bfloat16* __restrict__ xg,    // [T][NWG][4][32][16] (bias folded)
    const __hip_bfloat16* __restrict__ Whb,   // [G4][H]
    float* __restrict__ out,                  // [B][T][H] f32
    u64* __restrict__ tb)                     // [2][32][512] tagged h pairs
{
    extern __shared__ char smem[];
    float* gbuf = (float*)(smem + SMEM_GBUF);

    const int w    = blockIdx.x;
    const int tid  = threadIdx.x;
    const int lane = tid & 63;
    const int wave = tid >> 6;
    const int mwave = wave >> 2;
    const int q     = wave & 3;
    const int l15   = lane & 15;
    const int kg    = (lane >> 4) * 8;

    // ---- pin this wave's Wh B-fragments (UC loads; land in AGPRs) ----
    bf16x8 bfrag[32];
    {
        const char* wrow = (const char*)(Whb + (size_t)(q * 1024 + w * 16 + l15) * H_);
        #pragma unroll
        for (int i = 0; i < 32; ++i) {
            u64 lo = __hip_atomic_load((const u64*)(wrow + (i * 32 + kg) * 2),
                                       __ATOMIC_RELAXED, __HIP_MEMORY_SCOPE_AGENT);
            u64 hi = __hip_atomic_load((const u64*)(wrow + (i * 32 + kg) * 2 + 8),
                                       __ATOMIC_RELAXED, __HIP_MEMORY_SCOPE_AGENT);
            union { u64 qv[2]; bf16x8 v; } u;
            u.qv[0] = lo; u.qv[1] = hi;
            bfrag[i] = u.v;
        }
    }

    const int pb  = tid >> 4;          // batch 0..31
    const int pjj = tid & 15;
    const int jcol = w * 16 + pjj;
    float cst = 0.0f;

    const int dbr   = mwave * 16 + ((lane >> 4) << 2);
    const int arow  = mwave * 16 + l15;
    const int abase = arow * 2048;
    const int axor  = (arow & 7) << 4;
    const int srow  = wave * 4 + (lane >> 4);           // staging row 0..31
    const int ql    = lane & 15;

    for (int t = 0; t < T_; ++t) {
        // xg prefetch (independent of h; HBM latency hidden under the tag wait)
        float xgv[4];
        {
            const size_t sbase = (((size_t)t * NWG + w) * 4 + q) * 512;
            #pragma unroll
            for (int r = 0; r < 4; ++r)
                xgv[r] = __bfloat162float(xg[sbase + (dbr + r) * 16 + l15]);
        }

        f32x4 acc = {};
        if (t > 0) {
            // ---- stage h_{t-1}: tagged UC loads with retry, pack to swizzled LDS ----
            const u64* src = tb + ((size_t)((t - 1) & 1) * B_ + srow) * 512 + ql * 32;
            const u32 expect = (u32)(t - 1);
            #pragma unroll
            for (int half = 0; half < 2; ++half) {
                u64 g[16];
                #pragma unroll
                for (int j = 0; j < 16; ++j)
                    g[j] = __hip_atomic_load(src + half * 16 + j,
                                             __ATOMIC_RELAXED, __HIP_MEMORY_SCOPE_AGENT);
                #pragma unroll
                for (int j = 0; j < 16; ++j)
                    while ((u32)g[j] != expect)
                        g[j] = __hip_atomic_load(src + half * 16 + j,
                                                 __ATOMIC_RELAXED, __HIP_MEMORY_SCOPE_AGENT);
                #pragma unroll
                for (int c = 0; c < 4; ++c) {
                    uint4 pk;
                    pk.x = (u32)(g[c * 4 + 0] >> 32);
                    pk.y = (u32)(g[c * 4 + 1] >> 32);
                    pk.z = (u32)(g[c * 4 + 2] >> 32);
                    pk.w = (u32)(g[c * 4 + 3] >> 32);
                    const int byteoff = ql * 128 + half * 64 + c * 16;
                    *(uint4*)(smem + srow * 2048 + (byteoff ^ ((srow & 7) << 4))) = pk;
                }
            }
            __syncthreads();   // (A) stage -> MFMA; also fences prev-step gbuf reads

            // ---- 32 MFMAs, 4 accumulation chains ----
            f32x4 a0 = {}, a1 = {}, a2 = {}, a3 = {};
            #pragma unroll
            for (int i = 0; i < 8; ++i) {
                bf16x8 v0 = *(const bf16x8*)(smem + abase + ((((4 * i + 0) * 64) + kg * 2) ^ axor));
                bf16x8 v1 = *(const bf16x8*)(smem + abase + ((((4 * i + 1) * 64) + kg * 2) ^ axor));
                bf16x8 v2 = *(const bf16x8*)(smem + abase + ((((4 * i + 2) * 64) + kg * 2) ^ axor));
                bf16x8 v3 = *(const bf16x8*)(smem + abase + ((((4 * i + 3) * 64) + kg * 2) ^ axor));
                a0 = __builtin_amdgcn_mfma_f32_16x16x32_bf16(v0, bfrag[4 * i + 0], a0, 0, 0, 0);
                a1 = __builtin_amdgcn_mfma_f32_16x16x32_bf16(v1, bfrag[4 * i + 1], a1, 0, 0, 0);
                a2 = __builtin_amdgcn_mfma_f32_16x16x32_bf16(v2, bfrag[4 * i + 2], a2, 0, 0, 0);
                a3 = __builtin_amdgcn_mfma_f32_16x16x32_bf16(v3, bfrag[4 * i + 3], a3, 0, 0, 0);
            }
            acc = (a0 + a1) + (a2 + a3);
        }

        #pragma unroll
        for (int r = 0; r < 4; ++r)
            gbuf[((dbr + r) * 4 + q) * 17 + l15] = acc[r] + xgv[r];
        __syncthreads();   // (B) gbuf ready; also fences stage-LDS reads before next write

        // ---- pointwise; tagged publish first (critical), f32 out after (lazy) ----
        {
            float gi = sigm(gbuf[(pb * 4 + 0) * 17 + pjj]);
            float gf = sigm(gbuf[(pb * 4 + 1) * 17 + pjj]);
            float gg = sigm(gbuf[(pb * 4 + 2) * 17 + pjj]);  // sigmoid cell gate, per reference
            float go = sigm(gbuf[(pb * 4 + 3) * 17 + pjj]);
            cst = cst * gf + gi * gg;
            // tanh via exp identity (branch-free): tanh(c) = 1 - 2/(e^{2c}+1)
            float e2 = __expf(2.0f * cst);
            float h = go * (1.0f - 2.0f / (e2 + 1.0f));

            __hip_bfloat16 hb = __float2bfloat16(h);
            unsigned short hs_;
            __builtin_memcpy(&hs_, &hb, 2);
            u32 hu = hs_;
            u32 hup = __shfl_down(hu, 1, 64);
            if (!(pjj & 1)) {
                u64 val = ((u64)(hu | (hup << 16)) << 32) | (u64)(u32)t;
                __hip_atomic_store(tb + ((size_t)(t & 1) * B_ + pb) * 512 + w * 8 + (pjj >> 1),
                                   val, __ATOMIC_RELAXED, __HIP_MEMORY_SCOPE_AGENT);
            }
            out[((size_t)pb * T_ + t) * H_ + jcol] = h;   // off critical path
        }
    }
}

// ============ fallback (round-1 slow path) if ws too small ============
__global__ __launch_bounds__(256) void lstm_step(
    const float* __restrict__ inp, const float* __restrict__ Wx,
    const float* __restrict__ bx, const float* __restrict__ Wh,
    const float* __restrict__ bh, float* __restrict__ out,
    float* __restrict__ c_state, int t)
{
    const int tid = threadIdx.x;
    const int lane = tid & 63;
    const int khalf = lane & 1;
    const int b = lane >> 1;
    const int j = blockIdx.x * 4 + (tid >> 6);
    const int k0 = khalf * (D_ / 2);
    float a0 = 0.f, a1 = 0.f, a2 = 0.f, a3 = 0.f;
    {
        const float* xrow = inp + ((size_t)b * T_ + t) * D_ + k0;
        const float* w0 = Wx + (size_t)(0 * H_ + j) * D_ + k0;
        const float* w1 = Wx + (size_t)(1 * H_ + j) * D_ + k0;
        const float* w2 = Wx + (size_t)(2 * H_ + j) * D_ + k0;
        const float* w3 = Wx + (size_t)(3 * H_ + j) * D_ + k0;
        for (int kk = 0; kk < D_ / 2; kk += 4) {
            float4 xv = *(const float4*)(xrow + kk);
            float4 v0 = *(const float4*)(w0 + kk), v1 = *(const float4*)(w1 + kk);
            float4 v2 = *(const float4*)(w2 + kk), v3 = *(const float4*)(w3 + kk);
            a0 = fmaf(xv.x, v0.x, fmaf(xv.y, v0.y, fmaf(xv.z, v0.z, fmaf(xv.w, v0.w, a0))));
            a1 = fmaf(xv.x, v1.x, fmaf(xv.y, v1.y, fmaf(xv.z, v1.z, fmaf(xv.w, v1.w, a1))));
            a2 = fmaf(xv.x, v2.x, fmaf(xv.y, v2.y, fmaf(xv.z, v2.z, fmaf(xv.w, v2.w, a2))));
            a3 = fmaf(xv.x, v3.x, fmaf(xv.y, v3.y, fmaf(xv.z, v3.z, fmaf(xv.w, v3.w, a3))));
        }
    }
    if (t > 0) {
        const float* hrow = out + ((size_t)b * T_ + (t - 1)) * H_ + k0;
        const float* w0 = Wh + (size_t)(0 * H_ + j) * H_ + k0;
        const float* w1 = Wh + (size_t)(1 * H_ + j) * H_ + k0;
        const float* w2 = Wh + (size_t)(2 * H_ + j) * H_ + k0;
        const float* w3 = Wh + (size_t)(3 * H_ + j) * H_ + k0;
        for (int kk = 0; kk < H_ / 2; kk += 4) {
            float4 hv = *(const float4*)(hrow + kk);
            float4 v0 = *(const float4*)(w0 + kk), v1 = *(const float4*)(w1 + kk);
            float4 v2 = *(const float4*)(w2 + kk), v3 = *(const float4*)(w3 + kk);
            a0 = fmaf(hv.x, v0.x, fmaf(hv.y, v0.y, fmaf(hv.z, v0.z, fmaf(hv.w, v0.w, a0))));
            a1 = fmaf(hv.x, v1.x, fmaf(hv.y, v1.y, fmaf(hv.z, v1.z, fmaf(hv.w, v1.w, a1))));
            a2 = fmaf(hv.x, v2.x, fmaf(hv.y, v2.y, fmaf(hv.z, v2.z, fmaf(hv.w, v2.w, a2))));
            a3 = fmaf(hv.x, v3.x, fmaf(hv.y, v3.y, fmaf(hv.z, v3.z, fmaf(hv.w, v3.w, a3))));
        }
    }
    a0 += __shfl_xor(a0, 1, 64); a1 += __shfl_xor(a1, 1, 64);
    a2 += __shfl_xor(a2, 1, 64); a3 += __shfl_xor(a3, 1, 64);
    if (khalf == 0) {
        float gi = sigm(a0 + bx[0 * H_ + j] + bh[0 * H_ + j]);
        float gf = sigm(a1 + bx[1 * H_ + j] + bh[1 * H_ + j]);
        float gg = sigm(a2 + bx[2 * H_ + j] + bh[2 * H_ + j]);
        float go = sigm(a3 + bx[3 * H_ + j] + bh[3 * H_ + j]);
        size_t ci = (size_t)b * H_ + j;
        float c = (t > 0) ? c_state[ci] : 0.0f;
        c = c * gf + gi * gg;
        c_state[ci] = c;
        out[((size_t)b * T_ + t) * H_ + j] = go * tanhf(c);
    }
}

extern "C" void kernel_launch(void* const* d_in, const int* in_sizes, int n_in,
                              void* d_out, int out_size, void* d_ws, size_t ws_size,
                              hipStream_t stream) {
    const float* inp = (const float*)d_in[0];
    const float* Wx  = (const float*)d_in[1];
    const float* bx  = (const float*)d_in[2];
    const float* Wh  = (const float*)d_in[3];
    const float* bh  = (const float*)d_in[4];
    float* out = (float*)d_out;
    char* ws = (char*)d_ws;

    if (ws_size < WS_NEEDED) {
        float* c_state = (float*)d_ws;
        for (int t = 0; t < T_; ++t)
            lstm_step<<<dim3(H_ / 4), dim3(256), 0, stream>>>(inp, Wx, bx, Wh, bh, out, c_state, t);
        return;
    }

    u64*             tb    = (u64*)(ws + OFF_TB);
    __hip_bfloat16*  Whb   = (__hip_bfloat16*)(ws + OFF_WHB);
    __hip_bfloat16*  Wxb   = (__hip_bfloat16*)(ws + OFF_WXB);
    __hip_bfloat16*  inp_b = (__hip_bfloat16*)(ws + OFF_INPB);
    float*           bxh   = (float*)(ws + OFF_BXH);
    __hip_bfloat16*  xg    = (__hip_bfloat16*)(ws + OFF_XG);

    // invalidate all tags (0xFFFFFFFF != any t in [0,512)); captured in the graph,
    // so every replay starts clean — no cross-replay stale-tag hazard.
    hipMemsetAsync(tb, 0xFF, 262144, stream);

    convert_all<<<dim3(4096), dim3(256), 0, stream>>>(inp, Wx, bx, Wh, bh, inp_b, Wxb, Whb, bxh);

    xg_gemm<<<dim3(BT / 128, G4 / 128), dim3(256), 0, stream>>>(inp_b, Wxb, bxh, xg);

    static bool attr_set = false;
    if (!attr_set) {
        hipFuncSetAttribute((const void*)lstm_scan,
                            hipFuncAttributeMaxDynamicSharedMemorySize, SMEM_TOTAL);
        attr_set = true;
    }
    lstm_scan<<<dim3(NWG), dim3(512), SMEM_TOTAL, stream>>>(xg, Whb, out, tb);
}

// Round 9
// 2822.539 us; speedup vs baseline: 2.5763x; 2.5763x over previous
//
#include <hip/hip_runtime.h>
#include <hip/hip_bf16.h>
#include <math.h>

#define B_ 32
#define T_ 512
#define D_ 1024
#define H_ 1024
#define G4 4096
#define BT 16384
#define NWG 64

using bf16x8 = __attribute__((ext_vector_type(8))) short;
using f32x4  = __attribute__((ext_vector_type(4))) float;
typedef unsigned long long u64;
typedef unsigned int u32;

__device__ __forceinline__ float sigm(float x) { return 1.0f / (1.0f + __expf(-x)); }

// ---- workspace layout (bytes) ----
#define OFF_FLG   0ull                          // 512 per-wave flags, 64B stride = 32768
#define OFF_WHB   32768ull                      // Wh bf16 [4096][1024] = 8388608
#define OFF_WXB   (OFF_WHB + 8388608ull)        // Wx bf16 = 8388608
#define OFF_INPB  (OFF_WXB + 8388608ull)        // inp bf16 (reused as hseq[T][B][H]) = 33554432
#define OFF_BXH   (OFF_INPB + 33554432ull)      // bx+bh f32 [4096] = 16384
#define OFF_XG    (OFF_BXH + 16384ull)          // xg bf16 [T][NWG][4][32][16] = 134217728
#define WS_NEEDED (OFF_XG + 134217728ull)       // = 184598528

// scan LDS: [0,65536) h-stage 32x2048B swizzled; [65536,74240) gbuf [32][4][17] f32
#define SMEM_GBUF   65536
#define SMEM_TOTAL  74240

// ============ phase 1: convert inputs to bf16, fold biases ============
__global__ __launch_bounds__(256) void convert_all(
    const float* __restrict__ inp, const float* __restrict__ Wx,
    const float* __restrict__ bx, const float* __restrict__ Wh,
    const float* __restrict__ bh,
    __hip_bfloat16* __restrict__ inp_b, __hip_bfloat16* __restrict__ Wx_b,
    __hip_bfloat16* __restrict__ Wh_b, float* __restrict__ bxh)
{
    const int gid = blockIdx.x * 256 + threadIdx.x;   // 0 .. 1048575
    {
        const float4* s = (const float4*)inp + (size_t)gid * 4;
        #pragma unroll
        for (int v = 0; v < 4; ++v) {
            float4 f = s[v];
            size_t base = (size_t)gid * 16 + v * 4;
            inp_b[base + 0] = __float2bfloat16(f.x);
            inp_b[base + 1] = __float2bfloat16(f.y);
            inp_b[base + 2] = __float2bfloat16(f.z);
            inp_b[base + 3] = __float2bfloat16(f.w);
        }
    }
    {
        float4 fx = ((const float4*)Wx)[gid];
        float4 fh = ((const float4*)Wh)[gid];
        size_t base = (size_t)gid * 4;
        Wx_b[base + 0] = __float2bfloat16(fx.x);
        Wx_b[base + 1] = __float2bfloat16(fx.y);
        Wx_b[base + 2] = __float2bfloat16(fx.z);
        Wx_b[base + 3] = __float2bfloat16(fx.w);
        Wh_b[base + 0] = __float2bfloat16(fh.x);
        Wh_b[base + 1] = __float2bfloat16(fh.y);
        Wh_b[base + 2] = __float2bfloat16(fh.z);
        Wh_b[base + 3] = __float2bfloat16(fh.w);
    }
    if (gid < G4) bxh[gid] = bx[gid] + bh[gid];
}

// ============ phase 2: xg = X @ Wx^T + (bx+bh)  (128x128 LDS-staged, T2 swizzle) ============
__global__ __launch_bounds__(256) void xg_gemm(
    const __hip_bfloat16* __restrict__ X,    // [BT][D], row = b*T + t
    const __hip_bfloat16* __restrict__ Wxb,  // [G4][D]
    const float* __restrict__ bxh,           // [G4]
    __hip_bfloat16* __restrict__ xg)         // [T][NWG][4][32][16]
{
    __shared__ __align__(16) char As[16384];
    __shared__ __align__(16) char Bs[16384];

    const int m0 = blockIdx.x * 128;
    const int n0 = blockIdx.y * 128;
    const int tid = threadIdx.x;
    const int lane = tid & 63;
    const int wv = tid >> 6;              // 0..3
    const int vr = wv >> 1, vc = wv & 1;  // 64x64 quadrant
    const int l15 = lane & 15;
    const int kg = (lane >> 4) * 8;

    const int srow_ = wv * 32 + (lane >> 3);
    const int scolb = (lane & 7) * 16;

    f32x4 acc[4][4] = {};

    for (int k0 = 0; k0 < D_; k0 += 64) {
        #pragma unroll
        for (int c = 0; c < 4; ++c) {
            const int row = srow_ + c * 8;
            const int cb  = scolb ^ ((row & 7) << 4);
            const char* ga = (const char*)X   + (size_t)(m0 + row) * 2048 + k0 * 2 + cb;
            const char* gb = (const char*)Wxb + (size_t)(n0 + row) * 2048 + k0 * 2 + cb;
            __builtin_amdgcn_global_load_lds(
                (const __attribute__((address_space(1))) void*)ga,
                (__attribute__((address_space(3))) void*)(As + wv * 4096 + c * 1024),
                16, 0, 0);
            __builtin_amdgcn_global_load_lds(
                (const __attribute__((address_space(1))) void*)gb,
                (__attribute__((address_space(3))) void*)(Bs + wv * 4096 + c * 1024),
                16, 0, 0);
        }
        __syncthreads();

        #pragma unroll
        for (int kk = 0; kk < 64; kk += 32) {
            bf16x8 af[4], bf[4];
            #pragma unroll
            for (int mi = 0; mi < 4; ++mi) {
                const int row = vr * 64 + mi * 16 + l15;
                af[mi] = *(const bf16x8*)(As + row * 128 + (((kk + kg) * 2) ^ ((row & 7) << 4)));
            }
            #pragma unroll
            for (int ni = 0; ni < 4; ++ni) {
                const int col = vc * 64 + ni * 16 + l15;
                bf[ni] = *(const bf16x8*)(Bs + col * 128 + (((kk + kg) * 2) ^ ((col & 7) << 4)));
            }
            #pragma unroll
            for (int mi = 0; mi < 4; ++mi)
                #pragma unroll
                for (int ni = 0; ni < 4; ++ni)
                    acc[mi][ni] = __builtin_amdgcn_mfma_f32_16x16x32_bf16(
                        af[mi], bf[ni], acc[mi][ni], 0, 0, 0);
        }
        __syncthreads();
    }

    #pragma unroll
    for (int ni = 0; ni < 4; ++ni) {
        const int col = n0 + vc * 64 + ni * 16 + l15;
        const int qq = col >> 10, ww = (col >> 4) & 63, jj = col & 15;
        const float bias = bxh[col];
        #pragma unroll
        for (int mi = 0; mi < 4; ++mi) {
            const int r0 = m0 + vr * 64 + mi * 16 + ((lane >> 4) << 2);
            #pragma unroll
            for (int r = 0; r < 4; ++r) {
                const int row = r0 + r;                 // = b*T + t
                const int bb = row >> 9, tt = row & 511;
                xg[(((size_t)tt * NWG + ww) * 4 + qq) * 512 + bb * 16 + jj] =
                    __float2bfloat16(acc[mi][ni][r] + bias);
            }
        }
    }
}

// ============ phase 3: persistent recurrent scan — per-wave flags ============
// 64 WGs x 512 threads. Data paths identical to round 7 (proven 1710us):
// plain 16B h-stage loads -> swizzled LDS; 32 MFMA x4 chains; gbuf exchange.
// Sync restructured: producer wave publishes its own h slice (16 parallel u64 UC
// stores) + in-wave vmcnt(0) + per-wave flag. Consumer: 1 flag poll per THREAD
// (lane l of wave k polls flags[l*8+k]) -> one __syncthreads. No barrier C,
// no LDS relay, no hpack. f32 out written here after publish (shadow time).
__global__ __launch_bounds__(512) void lstm_scan(
    const __hip_bfloat16* __restrict__ xg,    // [T][NWG][4][32][16] (bias folded)
    const __hip_bfloat16* __restrict__ Whb,   // [G4][H]
    float* __restrict__ out,                  // [B][T][H] f32
    __hip_bfloat16* __restrict__ hseq,        // [T][B][H]
    unsigned int* __restrict__ flags)         // [NWG*8] at 64B stride
{
    extern __shared__ char smem[];
    float* gbuf = (float*)(smem + SMEM_GBUF);

    const int w    = blockIdx.x;
    const int tid  = threadIdx.x;
    const int lane = tid & 63;
    const int wave = tid >> 6;
    const int mwave = wave >> 2;
    const int q     = wave & 3;
    const int l15   = lane & 15;
    const int kg    = (lane >> 4) * 8;

    // ---- pin this wave's Wh B-fragments (UC loads; land in AGPRs) ----
    bf16x8 bfrag[32];
    {
        const char* wrow = (const char*)(Whb + (size_t)(q * 1024 + w * 16 + l15) * H_);
        #pragma unroll
        for (int i = 0; i < 32; ++i) {
            u64 lo = __hip_atomic_load((const u64*)(wrow + (i * 32 + kg) * 2),
                                       __ATOMIC_RELAXED, __HIP_MEMORY_SCOPE_AGENT);
            u64 hi = __hip_atomic_load((const u64*)(wrow + (i * 32 + kg) * 2 + 8),
                                       __ATOMIC_RELAXED, __HIP_MEMORY_SCOPE_AGENT);
            union { u64 qv[2]; bf16x8 v; } u;
            u.qv[0] = lo; u.qv[1] = hi;
            bfrag[i] = u.v;
        }
    }

    const int pb  = tid >> 4;          // batch 0..31
    const int pjj = tid & 15;
    const int jcol = w * 16 + pjj;
    float cst = 0.0f;

    const int dbr   = mwave * 16 + ((lane >> 4) << 2);
    const int arow  = mwave * 16 + l15;
    const int abase = arow * 2048;
    const int axor  = (arow & 7) << 4;
    const int srow  = wave * 4 + (lane >> 4);           // staging row 0..31
    const int ql    = lane & 15;

    // poll assignment: lane l of wave k polls producer (WG=l, wave=k)
    const unsigned int* myflag = flags + ((size_t)lane * 8 + wave) * 16;
    // publish flag for this (WG, wave)
    unsigned int* pubflag = flags + ((size_t)w * 8 + wave) * 16;

    for (int t = 0; t < T_; ++t) {
        // xg prefetch (independent of h; HBM latency hidden under the wait)
        float xgv[4];
        {
            const size_t sbase = (((size_t)t * NWG + w) * 4 + q) * 512;
            #pragma unroll
            for (int r = 0; r < 4; ++r)
                xgv[r] = __bfloat162float(xg[sbase + (dbr + r) * 16 + l15]);
        }

        f32x4 acc = {};
        if (t > 0) {
            // ---- arrival: each thread polls exactly one per-wave flag ----
            while (__hip_atomic_load(myflag, __ATOMIC_RELAXED, __HIP_MEMORY_SCOPE_AGENT)
                   < (unsigned)t)
                __builtin_amdgcn_s_sleep(1);
            __syncthreads();   // (P) all 512 producer-wave flags observed

            // ---- stage h_{t-1} into LDS (plain 16B loads, XOR-swizzled writes) ----
            {
                const bf16x8* src = (const bf16x8*)(hseq + ((size_t)(t - 1) * B_ + srow) * H_);
                #pragma unroll
                for (int j = 0; j < 8; ++j) {
                    bf16x8 v = src[ql + j * 16];
                    *(bf16x8*)(smem + srow * 2048 + (((ql + j * 16) * 16) ^ ((srow & 7) << 4))) = v;
                }
            }
            __syncthreads();   // (A)

            // ---- 32 MFMAs, 4 accumulation chains ----
            f32x4 a0 = {}, a1 = {}, a2 = {}, a3 = {};
            #pragma unroll
            for (int i = 0; i < 8; ++i) {
                bf16x8 v0 = *(const bf16x8*)(smem + abase + ((((4 * i + 0) * 64) + kg * 2) ^ axor));
                bf16x8 v1 = *(const bf16x8*)(smem + abase + ((((4 * i + 1) * 64) + kg * 2) ^ axor));
                bf16x8 v2 = *(const bf16x8*)(smem + abase + ((((4 * i + 2) * 64) + kg * 2) ^ axor));
                bf16x8 v3 = *(const bf16x8*)(smem + abase + ((((4 * i + 3) * 64) + kg * 2) ^ axor));
                a0 = __builtin_amdgcn_mfma_f32_16x16x32_bf16(v0, bfrag[4 * i + 0], a0, 0, 0, 0);
                a1 = __builtin_amdgcn_mfma_f32_16x16x32_bf16(v1, bfrag[4 * i + 1], a1, 0, 0, 0);
                a2 = __builtin_amdgcn_mfma_f32_16x16x32_bf16(v2, bfrag[4 * i + 2], a2, 0, 0, 0);
                a3 = __builtin_amdgcn_mfma_f32_16x16x32_bf16(v3, bfrag[4 * i + 3], a3, 0, 0, 0);
            }
            acc = (a0 + a1) + (a2 + a3);
        }

        #pragma unroll
        for (int r = 0; r < 4; ++r)
            gbuf[((dbr + r) * 4 + q) * 17 + l15] = acc[r] + xgv[r];
        __syncthreads();   // (B)

        // ---- pointwise; per-wave publish; f32 out after the flag ----
        {
            float gi = sigm(gbuf[(pb * 4 + 0) * 17 + pjj]);
            float gf = sigm(gbuf[(pb * 4 + 1) * 17 + pjj]);
            float gg = sigm(gbuf[(pb * 4 + 2) * 17 + pjj]);  // sigmoid cell gate, per reference
            float go = sigm(gbuf[(pb * 4 + 3) * 17 + pjj]);
            cst = cst * gf + gi * gg;
            float h = go * tanhf(cst);

            __hip_bfloat16 hb = __float2bfloat16(h);
            unsigned short hs_;
            __builtin_memcpy(&hs_, &hb, 2);
            u32 hu = hs_;
            u32 h1 = __shfl_down(hu, 1, 64);
            u32 h2 = __shfl_down(hu, 2, 64);
            u32 h3 = __shfl_down(hu, 3, 64);
            if ((pjj & 3) == 0) {
                u64 val = (u64)(hu | (h1 << 16)) | ((u64)(h2 | (h3 << 16)) << 32);
                u64* dst = (u64*)(hseq + ((size_t)t * B_ + pb) * H_ + jcol);
                __hip_atomic_store(dst, val, __ATOMIC_RELAXED, __HIP_MEMORY_SCOPE_AGENT);
            }
            // wave-level wait: this wave's 16 h-stores acked at coherence point
            asm volatile("s_waitcnt vmcnt(0)" ::: "memory");
            if (lane == 0 && t < T_ - 1)
                __hip_atomic_store(pubflag, (unsigned)(t + 1),
                                   __ATOMIC_RELAXED, __HIP_MEMORY_SCOPE_AGENT);
            out[((size_t)pb * T_ + t) * H_ + jcol] = h;   // off critical path
        }
    }
}

// ============ fallback (round-1 slow path) if ws too small ============
__global__ __launch_bounds__(256) void lstm_step(
    const float* __restrict__ inp, const float* __restrict__ Wx,
    const float* __restrict__ bx, const float* __restrict__ Wh,
    const float* __restrict__ bh, float* __restrict__ out,
    float* __restrict__ c_state, int t)
{
    const int tid = threadIdx.x;
    const int lane = tid & 63;
    const int khalf = lane & 1;
    const int b = lane >> 1;
    const int j = blockIdx.x * 4 + (tid >> 6);
    const int k0 = khalf * (D_ / 2);
    float a0 = 0.f, a1 = 0.f, a2 = 0.f, a3 = 0.f;
    {
        const float* xrow = inp + ((size_t)b * T_ + t) * D_ + k0;
        const float* w0 = Wx + (size_t)(0 * H_ + j) * D_ + k0;
        const float* w1 = Wx + (size_t)(1 * H_ + j) * D_ + k0;
        const float* w2 = Wx + (size_t)(2 * H_ + j) * D_ + k0;
        const float* w3 = Wx + (size_t)(3 * H_ + j) * D_ + k0;
        for (int kk = 0; kk < D_ / 2; kk += 4) {
            float4 xv = *(const float4*)(xrow + kk);
            float4 v0 = *(const float4*)(w0 + kk), v1 = *(const float4*)(w1 + kk);
            float4 v2 = *(const float4*)(w2 + kk), v3 = *(const float4*)(w3 + kk);
            a0 = fmaf(xv.x, v0.x, fmaf(xv.y, v0.y, fmaf(xv.z, v0.z, fmaf(xv.w, v0.w, a0))));
            a1 = fmaf(xv.x, v1.x, fmaf(xv.y, v1.y, fmaf(xv.z, v1.z, fmaf(xv.w, v1.w, a1))));
            a2 = fmaf(xv.x, v2.x, fmaf(xv.y, v2.y, fmaf(xv.z, v2.z, fmaf(xv.w, v2.w, a2))));
            a3 = fmaf(xv.x, v3.x, fmaf(xv.y, v3.y, fmaf(xv.z, v3.z, fmaf(xv.w, v3.w, a3))));
        }
    }
    if (t > 0) {
        const float* hrow = out + ((size_t)b * T_ + (t - 1)) * H_ + k0;
        const float* w0 = Wh + (size_t)(0 * H_ + j) * H_ + k0;
        const float* w1 = Wh + (size_t)(1 * H_ + j) * H_ + k0;
        const float* w2 = Wh + (size_t)(2 * H_ + j) * H_ + k0;
        const float* w3 = Wh + (size_t)(3 * H_ + j) * H_ + k0;
        for (int kk = 0; kk < H_ / 2; kk += 4) {
            float4 hv = *(const float4*)(hrow + kk);
            float4 v0 = *(const float4*)(w0 + kk), v1 = *(const float4*)(w1 + kk);
            float4 v2 = *(const float4*)(w2 + kk), v3 = *(const float4*)(w3 + kk);
            a0 = fmaf(hv.x, v0.x, fmaf(hv.y, v0.y, fmaf(hv.z, v0.z, fmaf(hv.w, v0.w, a0))));
            a1 = fmaf(hv.x, v1.x, fmaf(hv.y, v1.y, fmaf(hv.z, v1.z, fmaf(hv.w, v1.w, a1))));
            a2 = fmaf(hv.x, v2.x, fmaf(hv.y, v2.y, fmaf(hv.z, v2.z, fmaf(hv.w, v2.w, a2))));
            a3 = fmaf(hv.x, v3.x, fmaf(hv.y, v3.y, fmaf(hv.z, v3.w, fmaf(hv.w, v3.w, a3))));
        }
    }
    a0 += __shfl_xor(a0, 1, 64); a1 += __shfl_xor(a1, 1, 64);
    a2 += __shfl_xor(a2, 1, 64); a3 += __shfl_xor(a3, 1, 64);
    if (khalf == 0) {
        float gi = sigm(a0 + bx[0 * H_ + j] + bh[0 * H_ + j]);
        float gf = sigm(a1 + bx[1 * H_ + j] + bh[1 * H_ + j]);
        float gg = sigm(a2 + bx[2 * H_ + j] + bh[2 * H_ + j]);
        float go = sigm(a3 + bx[3 * H_ + j] + bh[3 * H_ + j]);
        size_t ci = (size_t)b * H_ + j;
        float c = (t > 0) ? c_state[ci] : 0.0f;
        c = c * gf + gi * gg;
        c_state[ci] = c;
        out[((size_t)b * T_ + t) * H_ + j] = go * tanhf(c);
    }
}

extern "C" void kernel_launch(void* const* d_in, const int* in_sizes, int n_in,
                              void* d_out, int out_size, void* d_ws, size_t ws_size,
                              hipStream_t stream) {
    const float* inp = (const float*)d_in[0];
    const float* Wx  = (const float*)d_in[1];
    const float* bx  = (const float*)d_in[2];
    const float* Wh  = (const float*)d_in[3];
    const float* bh  = (const float*)d_in[4];
    float* out = (float*)d_out;
    char* ws = (char*)d_ws;

    if (ws_size < WS_NEEDED) {
        float* c_state = (float*)d_ws;
        for (int t = 0; t < T_; ++t)
            lstm_step<<<dim3(H_ / 4), dim3(256), 0, stream>>>(inp, Wx, bx, Wh, bh, out, c_state, t);
        return;
    }

    unsigned int*    flags = (unsigned int*)(ws + OFF_FLG);
    __hip_bfloat16*  Whb   = (__hip_bfloat16*)(ws + OFF_WHB);
    __hip_bfloat16*  Wxb   = (__hip_bfloat16*)(ws + OFF_WXB);
    __hip_bfloat16*  inp_b = (__hip_bfloat16*)(ws + OFF_INPB);  // becomes hseq after xg_gemm
    float*           bxh   = (float*)(ws + OFF_BXH);
    __hip_bfloat16*  xg    = (__hip_bfloat16*)(ws + OFF_XG);
    __hip_bfloat16*  hseq  = inp_b;

    hipMemsetAsync(flags, 0, 32768, stream);

    convert_all<<<dim3(4096), dim3(256), 0, stream>>>(inp, Wx, bx, Wh, bh, inp_b, Wxb, Whb, bxh);

    xg_gemm<<<dim3(BT / 128, G4 / 128), dim3(256), 0, stream>>>(inp_b, Wxb, bxh, xg);

    static bool attr_set = false;
    if (!attr_set) {
        hipFuncSetAttribute((const void*)lstm_scan,
                            hipFuncAttributeMaxDynamicSharedMemorySize, SMEM_TOTAL);
        attr_set = true;
    }
    lstm_scan<<<dim3(NWG), dim3(512), SMEM_TOTAL, stream>>>(xg, Whb, out, hseq, flags);
}